// Round 1
// baseline (6056.072 us; speedup 1.0000x reference)
//
#include <hip/hip_runtime.h>
#include <stdint.h>

// Problem constants
#define BB 4
#define SS 8192
#define DD 1024
#define HH 8
#define DKK 128
#define EE 129            // DK + 1 (pos concat)
#define MM (BB * SS)      // 32768
#define KFC 1032          // H * E

__device__ __forceinline__ float bf2f(unsigned short u) {
    union { unsigned int i; float f; } v; v.i = ((unsigned int)u) << 16; return v.f;
}
__device__ __forceinline__ unsigned short f2bf(float f) {
    union { float f; unsigned int i; } v; v.f = f;
    unsigned int x = v.i;
    return (unsigned short)((x + 0x7FFFu + ((x >> 16) & 1u)) >> 16);
}

// ---------------------------------------------------------------------------
// Kernel 1: projection GEMM (y = X @ W^T + b), optional per-head LayerNorm,
// writes bf16 (B,H,S,E) with pos at e=0.
// Tile 64(M) x 128(N), block 16x16, each thread 4x8 outputs. N-tile == head.
// ---------------------------------------------------------------------------
__global__ __launch_bounds__(256)
void proj_ln(const float* __restrict__ X, const float* __restrict__ W,
             const float* __restrict__ bias, const float* __restrict__ g,
             const float* __restrict__ beta, const float* __restrict__ pos,
             unsigned short* __restrict__ out, int do_ln)
{
    __shared__ float Xs[64][20];
    __shared__ float Ws[128][20];
    const int tx = threadIdx.x, ty = threadIdx.y;
    const int t  = ty * 16 + tx;
    const int m0 = blockIdx.x * 64;
    const int h  = blockIdx.y;
    const int n0 = h * 128;

    float acc[4][8];
#pragma unroll
    for (int i = 0; i < 4; ++i)
#pragma unroll
        for (int j = 0; j < 8; ++j) acc[i][j] = 0.f;

    const int xr = t >> 2, xc = (t & 3) << 2;
    const int wn = t >> 1, wc = (t & 1) << 3;

    for (int k0 = 0; k0 < DD; k0 += 16) {
        *(float4*)&Xs[xr][xc] = *(const float4*)&X[(size_t)(m0 + xr) * DD + k0 + xc];
        *(float4*)&Ws[wn][wc]     = *(const float4*)&W[(size_t)(n0 + wn) * DD + k0 + wc];
        *(float4*)&Ws[wn][wc + 4] = *(const float4*)&W[(size_t)(n0 + wn) * DD + k0 + wc + 4];
        __syncthreads();
#pragma unroll
        for (int kk = 0; kk < 16; kk += 4) {
            float4 xa[4], wb[8];
#pragma unroll
            for (int i = 0; i < 4; ++i) xa[i] = *(const float4*)&Xs[ty * 4 + i][kk];
#pragma unroll
            for (int j = 0; j < 8; ++j) wb[j] = *(const float4*)&Ws[tx + 16 * j][kk];
#pragma unroll
            for (int i = 0; i < 4; ++i)
#pragma unroll
                for (int j = 0; j < 8; ++j)
                    acc[i][j] += xa[i].x * wb[j].x + xa[i].y * wb[j].y
                               + xa[i].z * wb[j].z + xa[i].w * wb[j].w;
        }
        __syncthreads();
    }

    // bias
#pragma unroll
    for (int j = 0; j < 8; ++j) {
        const float bb = bias[n0 + tx + 16 * j];
#pragma unroll
        for (int i = 0; i < 4; ++i) acc[i][j] += bb;
    }

    if (do_ln) {
#pragma unroll
        for (int i = 0; i < 4; ++i) {
            float s1 = 0.f, s2 = 0.f;
#pragma unroll
            for (int j = 0; j < 8; ++j) { s1 += acc[i][j]; s2 += acc[i][j] * acc[i][j]; }
#pragma unroll
            for (int msk = 1; msk < 16; msk <<= 1) {
                s1 += __shfl_xor(s1, msk);
                s2 += __shfl_xor(s2, msk);
            }
            const float mean = s1 * (1.f / 128.f);
            const float var  = s2 * (1.f / 128.f) - mean * mean;
            const float inv  = rsqrtf(var + 1e-5f);
#pragma unroll
            for (int j = 0; j < 8; ++j) {
                const int c = tx + 16 * j;
                acc[i][j] = (acc[i][j] - mean) * inv * g[n0 + c] + beta[n0 + c];
            }
        }
    }

#pragma unroll
    for (int i = 0; i < 4; ++i) {
        const int m = m0 + ty * 4 + i;
        const int b = m >> 13;            // / S
        const int s = m & (SS - 1);
        const size_t base = (((size_t)b * HH + h) * SS + s) * EE;
        if (tx == 0) out[base] = f2bf(pos[(size_t)b * SS + s]);
#pragma unroll
        for (int j = 0; j < 8; ++j)
            out[base + 1 + tx + 16 * j] = f2bf(acc[i][j]);
    }
}

// ---------------------------------------------------------------------------
// Kernel 2: p_attn[bh,d,e] = (1/S) * sum_s Kc[bh,s,d] * Vc[bh,s,e]
// Split-S with fp32 atomics. Block 256: 16x16 threads x (8x8) covers 128x128,
// border row d=128 / col e=128 handled by threads t<129 / t<128.
// ---------------------------------------------------------------------------
__global__ __launch_bounds__(256)
void patt(const unsigned short* __restrict__ Kc, const unsigned short* __restrict__ Vc,
          float* __restrict__ P)
{
    __shared__ float Ks[16][132];
    __shared__ float Vs[16][132];
    const int t  = threadIdx.x;
    const int bh = blockIdx.x;
    const int tx = t & 15, ty = t >> 4;
    const int d0 = ty * 8, e0 = tx * 8;
    const size_t base = (size_t)bh * SS * EE;

    float acc[8][8];
#pragma unroll
    for (int i = 0; i < 8; ++i)
#pragma unroll
        for (int j = 0; j < 8; ++j) acc[i][j] = 0.f;
    float accR = 0.f, accC = 0.f;

    const int sBeg = blockIdx.y * (SS / 16);
    const int sEnd = sBeg + (SS / 16);
    for (int s0 = sBeg; s0 < sEnd; s0 += 16) {
        for (int idx = t; idx < 16 * EE; idx += 256) {
            const int sl = idx / EE, e = idx - sl * EE;
            const size_t go = base + (size_t)(s0 + sl) * EE + e;
            Ks[sl][e] = bf2f(Kc[go]);
            Vs[sl][e] = bf2f(Vc[go]);
        }
        __syncthreads();
#pragma unroll
        for (int sl = 0; sl < 16; ++sl) {
            float kd[8], ve[8];
#pragma unroll
            for (int i = 0; i < 8; ++i) kd[i] = Ks[sl][d0 + i];
#pragma unroll
            for (int j = 0; j < 8; ++j) ve[j] = Vs[sl][e0 + j];
#pragma unroll
            for (int i = 0; i < 8; ++i)
#pragma unroll
                for (int j = 0; j < 8; ++j) acc[i][j] += kd[i] * ve[j];
            const float k128 = Ks[sl][128], v128 = Vs[sl][128];
            if (t < 129) accR += k128 * Vs[sl][t];
            if (t < 128) accC += Ks[sl][t] * v128;
        }
        __syncthreads();
    }
    const float sc = 1.f / (float)SS;
    float* Pp = P + (size_t)bh * (EE * EE);
#pragma unroll
    for (int i = 0; i < 8; ++i)
#pragma unroll
        for (int j = 0; j < 8; ++j)
            atomicAdd(&Pp[(d0 + i) * EE + (e0 + j)], acc[i][j] * sc);
    if (t < 129) atomicAdd(&Pp[128 * EE + t], accR * sc);
    if (t < 128) atomicAdd(&Pp[t * EE + 128], accC * sc);
}

// ---------------------------------------------------------------------------
// Kernel 3: x[b,s,h,e] = sum_d Qc[bh,s,d] * P[bh,d,e]   (bf16 out, (B,S,H,E))
// Block: 64 S-rows, Q tile + P chunk staged in LDS.
// ---------------------------------------------------------------------------
__global__ __launch_bounds__(256)
void xq(const unsigned short* __restrict__ Qc, const float* __restrict__ P,
        unsigned short* __restrict__ Xout)
{
    __shared__ float Qs[64][132];
    __shared__ float Ps[32][132];
    const int tx = threadIdx.x, ty = threadIdx.y;
    const int t  = ty * 16 + tx;
    const int bh = blockIdx.x;
    const int b = bh >> 3, h = bh & 7;
    const int s0 = blockIdx.y * 64;
    const size_t qbase = ((size_t)bh * SS + s0) * EE;

    for (int idx = t; idx < 64 * EE; idx += 256) {
        const int r = idx / EE, e = idx - r * EE;
        Qs[r][e] = bf2f(Qc[qbase + (size_t)r * EE + e]);
    }

    float acc[4][9];
#pragma unroll
    for (int i = 0; i < 4; ++i)
#pragma unroll
        for (int j = 0; j < 9; ++j) acc[i][j] = 0.f;

    const float* Pb = P + (size_t)bh * (EE * EE);
    for (int dc = 0; dc < EE; dc += 32) {
        const int csz = (EE - dc < 32) ? (EE - dc) : 32;
        for (int idx = t; idx < csz * EE; idx += 256) {
            const int r = idx / EE, e = idx - r * EE;
            Ps[r][e] = Pb[(dc + r) * EE + e];
        }
        __syncthreads();   // covers Qs (first iter) and Ps
        for (int dd = 0; dd < csz; ++dd) {
            float q[4];
#pragma unroll
            for (int i = 0; i < 4; ++i) q[i] = Qs[ty * 4 + i][dc + dd];
#pragma unroll
            for (int j = 0; j < 9; ++j) {
                const int c = tx + 16 * j;
                if (c < EE) {
                    const float pv = Ps[dd][c];
#pragma unroll
                    for (int i = 0; i < 4; ++i) acc[i][j] += q[i] * pv;
                }
            }
        }
        __syncthreads();   // before next Ps overwrite
    }

#pragma unroll
    for (int i = 0; i < 4; ++i) {
        const int s = s0 + ty * 4 + i;
        const size_t obase = (((size_t)b * SS + s) * HH + h) * EE;
#pragma unroll
        for (int j = 0; j < 9; ++j) {
            const int c = tx + 16 * j;
            if (c < EE) Xout[obase + c] = f2bf(acc[i][j]);
        }
    }
}

// ---------------------------------------------------------------------------
// Kernel 4: out = x @ Wfc^T + bfc.  x bf16 (M x 1032), Wfc fp32 (1024 x 1032),
// out fp32 (M x 1024). Tile 64x128 like kernel 1, K=1032 with tail guard.
// ---------------------------------------------------------------------------
__global__ __launch_bounds__(256)
void fcout(const unsigned short* __restrict__ Xc, const float* __restrict__ W,
           const float* __restrict__ bias, float* __restrict__ out)
{
    __shared__ float Xs[64][20];
    __shared__ float Ws[128][20];
    const int tx = threadIdx.x, ty = threadIdx.y;
    const int t  = ty * 16 + tx;
    const int m0 = blockIdx.x * 64;
    const int n0 = blockIdx.y * 128;

    float acc[4][8];
#pragma unroll
    for (int i = 0; i < 4; ++i)
#pragma unroll
        for (int j = 0; j < 8; ++j) acc[i][j] = 0.f;

    const int xr = t >> 2, xc = (t & 3) << 2;
    const int wn = t >> 1, wc = (t & 1) << 3;

    for (int k0 = 0; k0 < KFC; k0 += 16) {
        {
            const int k = k0 + xc;
            if (k < KFC) {
                const ushort4 u = *(const ushort4*)&Xc[(size_t)(m0 + xr) * KFC + k];
                Xs[xr][xc]     = bf2f(u.x);
                Xs[xr][xc + 1] = bf2f(u.y);
                Xs[xr][xc + 2] = bf2f(u.z);
                Xs[xr][xc + 3] = bf2f(u.w);
            } else {
                Xs[xr][xc] = 0.f; Xs[xr][xc + 1] = 0.f;
                Xs[xr][xc + 2] = 0.f; Xs[xr][xc + 3] = 0.f;
            }
        }
        {
            const int k = k0 + wc;
            if (k < KFC) {
                *(float4*)&Ws[wn][wc] = *(const float4*)&W[(size_t)(n0 + wn) * KFC + k];
            } else {
                Ws[wn][wc] = 0.f; Ws[wn][wc + 1] = 0.f; Ws[wn][wc + 2] = 0.f; Ws[wn][wc + 3] = 0.f;
            }
            if (k + 4 < KFC) {
                *(float4*)&Ws[wn][wc + 4] = *(const float4*)&W[(size_t)(n0 + wn) * KFC + k + 4];
            } else {
                Ws[wn][wc + 4] = 0.f; Ws[wn][wc + 5] = 0.f; Ws[wn][wc + 6] = 0.f; Ws[wn][wc + 7] = 0.f;
            }
        }
        __syncthreads();
#pragma unroll
        for (int kk = 0; kk < 16; kk += 4) {
            float4 xa[4], wb[8];
#pragma unroll
            for (int i = 0; i < 4; ++i) xa[i] = *(const float4*)&Xs[ty * 4 + i][kk];
#pragma unroll
            for (int j = 0; j < 8; ++j) wb[j] = *(const float4*)&Ws[tx + 16 * j][kk];
#pragma unroll
            for (int i = 0; i < 4; ++i)
#pragma unroll
                for (int j = 0; j < 8; ++j)
                    acc[i][j] += xa[i].x * wb[j].x + xa[i].y * wb[j].y
                               + xa[i].z * wb[j].z + xa[i].w * wb[j].w;
        }
        __syncthreads();
    }

#pragma unroll
    for (int j = 0; j < 8; ++j) {
        const float bb = bias[n0 + tx + 16 * j];
#pragma unroll
        for (int i = 0; i < 4; ++i) acc[i][j] += bb;
    }

#pragma unroll
    for (int i = 0; i < 4; ++i) {
        const int m = m0 + ty * 4 + i;
#pragma unroll
        for (int j = 0; j < 8; ++j)
            out[(size_t)m * DD + n0 + tx + 16 * j] = acc[i][j];
    }
}

// ---------------------------------------------------------------------------
extern "C" void kernel_launch(void* const* d_in, const int* in_sizes, int n_in,
                              void* d_out, int out_size, void* d_ws, size_t ws_size,
                              hipStream_t stream)
{
    const float* query = (const float*)d_in[0];
    const float* key   = (const float*)d_in[1];
    const float* value = (const float*)d_in[2];
    const float* pos   = (const float*)d_in[3];
    const float* Wq    = (const float*)d_in[4];
    const float* bq    = (const float*)d_in[5];
    const float* Wk    = (const float*)d_in[6];
    const float* bk    = (const float*)d_in[7];
    const float* Wv    = (const float*)d_in[8];
    const float* bv    = (const float*)d_in[9];
    const float* gK    = (const float*)d_in[10];
    const float* betaK = (const float*)d_in[11];
    const float* gV    = (const float*)d_in[12];
    const float* betaV = (const float*)d_in[13];
    const float* Wfc   = (const float*)d_in[14];
    const float* bfc   = (const float*)d_in[15];
    float* out = (float*)d_out;

    char* ws = (char*)d_ws;
    const size_t QBYTES = (size_t)BB * HH * SS * EE * 2;  // 67,633,152 B each
    unsigned short* Qc = (unsigned short*)(ws);
    unsigned short* Kc = (unsigned short*)(ws + QBYTES);
    unsigned short* Vc = (unsigned short*)(ws + 2 * QBYTES);
    float* P           = (float*)(ws + 3 * QBYTES);       // 2,130,048 B
    unsigned short* Xb = Kc;  // alias: Kc dead after patt; x overwrites it

    dim3 blk(16, 16);
    proj_ln<<<dim3(MM / 64, HH), blk, 0, stream>>>(query, Wq, bq, nullptr, nullptr, pos, Qc, 0);
    proj_ln<<<dim3(MM / 64, HH), blk, 0, stream>>>(key,   Wk, bk, gK, betaK, pos, Kc, 1);
    proj_ln<<<dim3(MM / 64, HH), blk, 0, stream>>>(value, Wv, bv, gV, betaV, pos, Vc, 1);
    hipMemsetAsync(P, 0, (size_t)BB * HH * EE * EE * sizeof(float), stream);
    patt<<<dim3(BB * HH, 16), dim3(256), 0, stream>>>(Kc, Vc, P);
    xq<<<dim3(BB * HH, SS / 64), blk, 0, stream>>>(Qc, P, Xb);
    fcout<<<dim3(MM / 64, DD / 128), blk, 0, stream>>>(Xb, Wfc, bfc, out);
}

// Round 2
// 1935.706 us; speedup vs baseline: 3.1286x; 3.1286x over previous
//
#include <hip/hip_runtime.h>
#include <stdint.h>

#define BB 4
#define SS 8192
#define DD 1024
#define HH 8
#define DKK 128
#define EE 129            // DK + 1 (pos concat)
#define MM (BB * SS)      // 32768

typedef __attribute__((ext_vector_type(8))) short short8;
typedef __attribute__((ext_vector_type(4))) float floatx4;

__device__ __forceinline__ float bf2f(unsigned short u) {
    union { unsigned int i; float f; } v; v.i = ((unsigned int)u) << 16; return v.f;
}
__device__ __forceinline__ unsigned short f2bf(float f) {
    union { float f; unsigned int i; } v; v.f = f;
    unsigned int x = v.i;
    return (unsigned short)((x + 0x7FFFu + ((x >> 16) & 1u)) >> 16);
}

__device__ __forceinline__ void gld_lds16(const unsigned short* g, unsigned short* l) {
    __builtin_amdgcn_global_load_lds((const __attribute__((address_space(1))) void*)g,
                                     (__attribute__((address_space(3))) void*)l, 16, 0, 0);
}

// ---------------------------------------------------------------------------
// fp32 -> bf16 elementwise (vectorized), n4 = count of float4 groups
// ---------------------------------------------------------------------------
__global__ __launch_bounds__(256)
void conv_bf16(const float* __restrict__ in, unsigned short* __restrict__ out, int n4)
{
    int idx = blockIdx.x * 256 + threadIdx.x;
    const int stride = gridDim.x * 256;
    for (; idx < n4; idx += stride) {
        const float4 v = ((const float4*)in)[idx];
        ushort4 o;
        o.x = f2bf(v.x); o.y = f2bf(v.y); o.z = f2bf(v.z); o.w = f2bf(v.w);
        ((ushort4*)out)[idx] = o;
    }
}

// Wfc (1024 x 1032) fp32 -> (1024 x 1088) bf16, pad K with zeros
__global__ __launch_bounds__(256)
void conv_wfc(const float* __restrict__ in, unsigned short* __restrict__ out)
{
    int idx = blockIdx.x * 256 + threadIdx.x;
    const int stride = gridDim.x * 256;
    const int total = 1024 * 1088;
    for (; idx < total; idx += stride) {
        const int n = idx / 1088, k = idx - n * 1088;
        out[idx] = (k < 1032) ? f2bf(in[n * 1032 + k]) : (unsigned short)0;
    }
}

// ---------------------------------------------------------------------------
// MFMA GEMM: C = A @ B^T (+bias). A (M,K) bf16 row-major, B (N,K) bf16
// row-major. 128x128 tile, BK=64, 4 waves, 16x16x32 bf16 MFMA, 4x4 frags.
// MODE 0: fp32 C (M,1024) + bias         (final fc)
// MODE 1: bf16 out (B,H,S,129) + bias + pos at e=0        (Q projection)
// MODE 2: MODE 1 + per-head LayerNorm (g, beta)           (K/V projections)
// grid: (N/128, M/128)  -> n0 = bx*128 (head for MODE1/2), m0 = by*128
// ---------------------------------------------------------------------------
template<int MODE>
__global__ __launch_bounds__(256)
void gemm_bt(const unsigned short* __restrict__ A, const unsigned short* __restrict__ Bm,
             int K, const float* __restrict__ bias,
             const float* __restrict__ g, const float* __restrict__ beta,
             const float* __restrict__ pos,
             float* __restrict__ Cf, unsigned short* __restrict__ Cb)
{
    __shared__ unsigned short As[128 * 64];
    __shared__ unsigned short Bs[128 * 64];
    __shared__ float red[128][4];

    const int tid  = threadIdx.x;
    const int lane = tid & 63, wid = tid >> 6;
    const int lr = lane & 15, lg = lane >> 4;
    const int wm = wid >> 1,  wn = wid & 1;
    const int n0 = blockIdx.x * 128;
    const int m0 = blockIdx.y * 128;

    floatx4 acc[4][4];
#pragma unroll
    for (int i = 0; i < 4; ++i)
#pragma unroll
        for (int j = 0; j < 4; ++j) acc[i][j] = (floatx4){0.f, 0.f, 0.f, 0.f};

    const int srow = lane >> 3;        // 0..7
    const int scol = (lane & 7) * 8;   // k offset (shorts) within the 64-wide tile

    for (int k0 = 0; k0 < K; k0 += 64) {
#pragma unroll
        for (int c = 0; c < 4; ++c) {
            const int j = wid * 4 + c;                   // 0..15: 8 rows per call
            const unsigned short* gA = A  + (size_t)(m0 + j * 8 + srow) * K + (k0 + scol);
            const unsigned short* gB = Bm + (size_t)(n0 + j * 8 + srow) * K + (k0 + scol);
            gld_lds16(gA, &As[j * 512]);
            gld_lds16(gB, &Bs[j * 512]);
        }
        __syncthreads();
#pragma unroll
        for (int kk = 0; kk < 64; kk += 32) {
            short8 af[4], bf[4];
#pragma unroll
            for (int f = 0; f < 4; ++f) {
                af[f] = *(const short8*)&As[(wm * 64 + f * 16 + lr) * 64 + kk + lg * 8];
                bf[f] = *(const short8*)&Bs[(wn * 64 + f * 16 + lr) * 64 + kk + lg * 8];
            }
#pragma unroll
            for (int fi = 0; fi < 4; ++fi)
#pragma unroll
                for (int fj = 0; fj < 4; ++fj)
                    acc[fi][fj] = __builtin_amdgcn_mfma_f32_16x16x32_bf16(
                        af[fi], bf[fj], acc[fi][fj], 0, 0, 0);
        }
        __syncthreads();
    }

    // bias (reference adds bias before LN)
    float bb[4];
#pragma unroll
    for (int fj = 0; fj < 4; ++fj) bb[fj] = bias[n0 + wn * 64 + fj * 16 + lr];
#pragma unroll
    for (int fi = 0; fi < 4; ++fi)
#pragma unroll
        for (int fj = 0; fj < 4; ++fj)
#pragma unroll
            for (int r = 0; r < 4; ++r) acc[fi][fj][r] += bb[fj];

    if (MODE == 0) {
#pragma unroll
        for (int fi = 0; fi < 4; ++fi)
#pragma unroll
            for (int r = 0; r < 4; ++r) {
                const int m = m0 + wm * 64 + fi * 16 + lg * 4 + r;
#pragma unroll
                for (int fj = 0; fj < 4; ++fj)
                    Cf[(size_t)m * 1024 + n0 + wn * 64 + fj * 16 + lr] = acc[fi][fj][r];
            }
        return;
    }

    if (MODE == 2) {
        float gv[4], bv[4];
#pragma unroll
        for (int fj = 0; fj < 4; ++fj) {
            gv[fj] = g[n0 + wn * 64 + fj * 16 + lr];     // g is (H,128) flat = 1024
            bv[fj] = beta[n0 + wn * 64 + fj * 16 + lr];
        }
        // per-row partial sums over this wave's 64 cols, then cross-wave via LDS
#pragma unroll
        for (int fi = 0; fi < 4; ++fi)
#pragma unroll
            for (int r = 0; r < 4; ++r) {
                float p1 = 0.f, p2 = 0.f;
#pragma unroll
                for (int fj = 0; fj < 4; ++fj) {
                    const float v = acc[fi][fj][r];
                    p1 += v; p2 += v * v;
                }
#pragma unroll
                for (int msk = 1; msk < 16; msk <<= 1) {
                    p1 += __shfl_xor(p1, msk);
                    p2 += __shfl_xor(p2, msk);
                }
                if (lr == 0) {
                    const int row = wm * 64 + fi * 16 + lg * 4 + r;
                    red[row][wn * 2]     = p1;
                    red[row][wn * 2 + 1] = p2;
                }
            }
        __syncthreads();
#pragma unroll
        for (int fi = 0; fi < 4; ++fi)
#pragma unroll
            for (int r = 0; r < 4; ++r) {
                const int row = wm * 64 + fi * 16 + lg * 4 + r;
                const float s1 = red[row][0] + red[row][2];
                const float s2 = red[row][1] + red[row][3];
                const float mean = s1 * (1.f / 128.f);
                const float var  = s2 * (1.f / 128.f) - mean * mean;
                const float inv  = rsqrtf(var + 1e-5f);
#pragma unroll
                for (int fj = 0; fj < 4; ++fj)
                    acc[fi][fj][r] = (acc[fi][fj][r] - mean) * inv * gv[fj] + bv[fj];
            }
    }

    // store bf16 (B,H,S,129), pos at e=0
    const int h = n0 >> 7;
#pragma unroll
    for (int fi = 0; fi < 4; ++fi)
#pragma unroll
        for (int r = 0; r < 4; ++r) {
            const int m = m0 + wm * 64 + fi * 16 + lg * 4 + r;
            const int b = m >> 13, s = m & (SS - 1);
            const size_t base = (((size_t)b * HH + h) * SS + s) * EE;
#pragma unroll
            for (int fj = 0; fj < 4; ++fj)
                Cb[base + 1 + wn * 64 + fj * 16 + lr] = f2bf(acc[fi][fj][r]);
            if (wn == 0 && lr == 0)
                Cb[base] = f2bf(pos[((size_t)b << 13) + s]);
        }
}

// ---------------------------------------------------------------------------
// p_attn[bh,d,e] = (1/S) * sum_s Kc[bh,s,d] * Vc[bh,s,e]   (unchanged R1)
// ---------------------------------------------------------------------------
__global__ __launch_bounds__(256)
void patt(const unsigned short* __restrict__ Kc, const unsigned short* __restrict__ Vc,
          float* __restrict__ P)
{
    __shared__ float Ks[16][132];
    __shared__ float Vs[16][132];
    const int t  = threadIdx.x;
    const int bh = blockIdx.x;
    const int tx = t & 15, ty = t >> 4;
    const int d0 = ty * 8, e0 = tx * 8;
    const size_t base = (size_t)bh * SS * EE;

    float acc[8][8];
#pragma unroll
    for (int i = 0; i < 8; ++i)
#pragma unroll
        for (int j = 0; j < 8; ++j) acc[i][j] = 0.f;
    float accR = 0.f, accC = 0.f;

    const int sBeg = blockIdx.y * (SS / 16);
    const int sEnd = sBeg + (SS / 16);
    for (int s0 = sBeg; s0 < sEnd; s0 += 16) {
        for (int idx = t; idx < 16 * EE; idx += 256) {
            const int sl = idx / EE, e = idx - sl * EE;
            const size_t go = base + (size_t)(s0 + sl) * EE + e;
            Ks[sl][e] = bf2f(Kc[go]);
            Vs[sl][e] = bf2f(Vc[go]);
        }
        __syncthreads();
#pragma unroll
        for (int sl = 0; sl < 16; ++sl) {
            float kd[8], ve[8];
#pragma unroll
            for (int i = 0; i < 8; ++i) kd[i] = Ks[sl][d0 + i];
#pragma unroll
            for (int j = 0; j < 8; ++j) ve[j] = Vs[sl][e0 + j];
#pragma unroll
            for (int i = 0; i < 8; ++i)
#pragma unroll
                for (int j = 0; j < 8; ++j) acc[i][j] += kd[i] * ve[j];
            const float k128 = Ks[sl][128], v128 = Vs[sl][128];
            if (t < 129) accR += k128 * Vs[sl][t];
            if (t < 128) accC += Ks[sl][t] * v128;
        }
        __syncthreads();
    }
    const float sc = 1.f / (float)SS;
    float* Pp = P + (size_t)bh * (EE * EE);
#pragma unroll
    for (int i = 0; i < 8; ++i)
#pragma unroll
        for (int j = 0; j < 8; ++j)
            atomicAdd(&Pp[(d0 + i) * EE + (e0 + j)], acc[i][j] * sc);
    if (t < 129) atomicAdd(&Pp[128 * EE + t], accR * sc);
    if (t < 128) atomicAdd(&Pp[t * EE + 128], accC * sc);
}

// ---------------------------------------------------------------------------
// x[b,s, h*129+e] = sum_d Qc[bh,s,d] * P[bh,d,e]; bf16 out rows padded to 1088
// ---------------------------------------------------------------------------
__global__ __launch_bounds__(256)
void xq(const unsigned short* __restrict__ Qc, const float* __restrict__ P,
        unsigned short* __restrict__ Xout)
{
    __shared__ float Qs[64][132];
    __shared__ float Ps[32][132];
    const int tx = threadIdx.x, ty = threadIdx.y;
    const int t  = ty * 16 + tx;
    const int bh = blockIdx.x;
    const int b = bh >> 3, h = bh & 7;
    const int s0 = blockIdx.y * 64;
    const size_t qbase = ((size_t)bh * SS + s0) * EE;

    for (int idx = t; idx < 64 * EE; idx += 256) {
        const int r = idx / EE, e = idx - r * EE;
        Qs[r][e] = bf2f(Qc[qbase + (size_t)r * EE + e]);
    }

    float acc[4][9];
#pragma unroll
    for (int i = 0; i < 4; ++i)
#pragma unroll
        for (int j = 0; j < 9; ++j) acc[i][j] = 0.f;

    const float* Pb = P + (size_t)bh * (EE * EE);
    for (int dc = 0; dc < EE; dc += 32) {
        const int csz = (EE - dc < 32) ? (EE - dc) : 32;
        for (int idx = t; idx < csz * EE; idx += 256) {
            const int r = idx / EE, e = idx - r * EE;
            Ps[r][e] = Pb[(dc + r) * EE + e];
        }
        __syncthreads();
        for (int dd = 0; dd < csz; ++dd) {
            float q[4];
#pragma unroll
            for (int i = 0; i < 4; ++i) q[i] = Qs[ty * 4 + i][dc + dd];
#pragma unroll
            for (int j = 0; j < 9; ++j) {
                const int c = tx + 16 * j;
                if (c < EE) {
                    const float pv = Ps[dd][c];
#pragma unroll
                    for (int i = 0; i < 4; ++i) acc[i][j] += q[i] * pv;
                }
            }
        }
        __syncthreads();
    }

#pragma unroll
    for (int i = 0; i < 4; ++i) {
        const int s = s0 + ty * 4 + i;
        const size_t obase = ((size_t)b * SS + s) * 1088 + (size_t)h * EE;
#pragma unroll
        for (int j = 0; j < 9; ++j) {
            const int c = tx + 16 * j;
            if (c < EE) Xout[obase + c] = f2bf(acc[i][j]);
        }
    }
}

// ---------------------------------------------------------------------------
extern "C" void kernel_launch(void* const* d_in, const int* in_sizes, int n_in,
                              void* d_out, int out_size, void* d_ws, size_t ws_size,
                              hipStream_t stream)
{
    const float* query = (const float*)d_in[0];
    const float* key   = (const float*)d_in[1];
    const float* value = (const float*)d_in[2];
    const float* pos   = (const float*)d_in[3];
    const float* Wq    = (const float*)d_in[4];
    const float* bq    = (const float*)d_in[5];
    const float* Wk    = (const float*)d_in[6];
    const float* bk    = (const float*)d_in[7];
    const float* Wv    = (const float*)d_in[8];
    const float* bv    = (const float*)d_in[9];
    const float* gK    = (const float*)d_in[10];
    const float* betaK = (const float*)d_in[11];
    const float* gV    = (const float*)d_in[12];
    const float* betaV = (const float*)d_in[13];
    const float* Wfc   = (const float*)d_in[14];
    const float* bfc   = (const float*)d_in[15];
    float* out = (float*)d_out;

    // Workspace regions (total 205,029,504 B — identical footprint to R1):
    //   REG_A @ 0      : bf16 X input staging (67.63 MB); later padded x (spills 3.67 MB into REG_B)
    //   REG_B @ R      : Kc; later Wq-bf16 (head) then x-spill; WfcB at +8 MB
    //   REG_C @ 2R     : Vc; later Qc
    //   PREG  @ 3R     : W-bf16 during projections; then p_attn (2.13 MB)
    char* ws = (char*)d_ws;
    const size_t R = (size_t)BB * HH * SS * EE * 2;   // 67,633,152
    unsigned short* XA   = (unsigned short*)(ws);
    unsigned short* RB   = (unsigned short*)(ws + R);
    unsigned short* RC   = (unsigned short*)(ws + 2 * R);
    float*          P    = (float*)(ws + 3 * R);
    unsigned short* WB   = (unsigned short*)(ws + 3 * R);
    unsigned short* WqB  = RB;
    unsigned short* Xb   = XA;                                   // (32768 x 1088) bf16
    unsigned short* WfcB = (unsigned short*)(ws + R + (8u << 20));

    const dim3 gblk(256);
    const dim3 ggrid(8, 256);   // (N/128, M/128)

    // K projection
    conv_bf16<<<256, gblk, 0, stream>>>(Wk, WB, 262144);
    conv_bf16<<<2048, gblk, 0, stream>>>(key, XA, 8388608);
    gemm_bt<2><<<ggrid, gblk, 0, stream>>>(XA, WB, 1024, bk, gK, betaK, pos, nullptr, RB);
    // V projection
    conv_bf16<<<256, gblk, 0, stream>>>(Wv, WB, 262144);
    conv_bf16<<<2048, gblk, 0, stream>>>(value, XA, 8388608);
    gemm_bt<2><<<ggrid, gblk, 0, stream>>>(XA, WB, 1024, bv, gV, betaV, pos, nullptr, RC);
    // p_attn
    hipMemsetAsync(P, 0, (size_t)BB * HH * EE * EE * sizeof(float), stream);
    patt<<<dim3(BB * HH, 16), gblk, 0, stream>>>(RB, RC, P);
    // Q projection (Kc/Vc regions now dead)
    conv_bf16<<<256, gblk, 0, stream>>>(Wq, WqB, 262144);
    conv_bf16<<<2048, gblk, 0, stream>>>(query, XA, 8388608);
    gemm_bt<1><<<ggrid, gblk, 0, stream>>>(XA, WqB, 1024, bq, nullptr, nullptr, pos, nullptr, RC);
    // x = Q @ p_attn  (padded rows of 1088, written over REG_A + spill)
    xq<<<dim3(BB * HH, SS / 64), dim3(16, 16), 0, stream>>>(RC, P, Xb);
    // final fc
    conv_wfc<<<1024, gblk, 0, stream>>>(Wfc, WfcB);
    gemm_bt<0><<<ggrid, gblk, 0, stream>>>(Xb, WfcB, 1088, bfc, nullptr, nullptr, nullptr, out, nullptr);
}